// Round 5
// baseline (3008.681 us; speedup 1.0000x reference)
//
#include <hip/hip_runtime.h>
#include <hip/hip_fp16.h>

#define N_USERS 100000
#define N_ITEMS 200000
#define N_TOTAL 300000
#define N_EDGES 6000000
#define D 64

#define RPB 64                               // rows per bucket (power of 2)
#define NB ((N_TOTAL + RPB - 1) / RPB)       // 4688 buckets
#define R_REP 32                             // cursor replicas (contention /32)
#define SCAN_N (NB * R_REP)                  // 150016

// ---------------------------------------------------------------------------
// trans(fp16) = all_feat @ W^T + b  (one wave per row). fp16 halves gather
// traffic in bucket_pull; |trans| <~ 12 so fp16 is safe (err ~5e-3 << 0.595).
// ---------------------------------------------------------------------------
__global__ __launch_bounds__(256) void linear_half_kernel(
    const float* __restrict__ user_feat,
    const float* __restrict__ item_feat,
    const float* __restrict__ W,
    const float* __restrict__ b,
    __half* __restrict__ trans)
{
    __shared__ float Ws[D][D + 1];
    __shared__ float bs[D];
    const int t = threadIdx.x;
    for (int i = t; i < D * D; i += 256) Ws[i >> 6][i & 63] = W[i];
    if (t < D) bs[t] = b[t];
    __syncthreads();

    const int lane = t & 63;
    const int row  = blockIdx.x * 4 + (t >> 6);
    if (row >= N_TOTAL) return;

    const float* feat = (row < N_USERS)
        ? user_feat + (size_t)row * D
        : item_feat + (size_t)(row - N_USERS) * D;

    const float fv = feat[lane];
    float acc = bs[lane];
    #pragma unroll
    for (int k = 0; k < D; ++k)
        acc = fmaf(__shfl(fv, k, 64), Ws[lane][k], acc);

    trans[(size_t)row * D + lane] = __float2half(acc);
}

// ---------------------------------------------------------------------------
// Bucket histogram: counters replicated 32x, replica-major so replicas of one
// bucket live on different cache lines. 4 edges/thread.
// ---------------------------------------------------------------------------
__global__ __launch_bounds__(256) void bhist_kernel(
    const int* __restrict__ A_row, int* __restrict__ cnt)
{
    const int e0 = (blockIdx.x * 256 + threadIdx.x) * 4;
    if (e0 >= N_EDGES) return;
    int* c = cnt + (blockIdx.x & (R_REP - 1)) * NB;
    const int4 r = *reinterpret_cast<const int4*>(A_row + e0);
    atomicAdd(&c[r.x >> 6], 1);
    atomicAdd(&c[r.y >> 6], 1);
    atomicAdd(&c[r.z >> 6], 1);
    atomicAdd(&c[r.w >> 6], 1);
}

// ---------------------------------------------------------------------------
// Exclusive scan over (bucket-major, replica-minor) logical order; storage is
// replica-major. In-place: cnt becomes per-(bucket,replica) cursors. Writes
// boff[b] (bucket starts) and boff[NB] = N_EDGES. Single block.
// ---------------------------------------------------------------------------
__global__ __launch_bounds__(1024) void bscan_kernel(
    int* __restrict__ cnt, int* __restrict__ boff)
{
    __shared__ int ps[1024];
    const int t = threadIdx.x;
    const int ITEMS = (SCAN_N + 1023) / 1024;   // 147
    const int s0 = t * ITEMS;

    int sum = 0;
    for (int k = 0; k < ITEMS; ++k) {
        const int s = s0 + k;
        if (s < SCAN_N) sum += cnt[(s & (R_REP - 1)) * NB + (s >> 5)];
    }
    ps[t] = sum;
    __syncthreads();
    for (int d = 1; d < 1024; d <<= 1) {
        const int x = (t >= d) ? ps[t - d] : 0;
        __syncthreads();
        ps[t] += x;
        __syncthreads();
    }
    int run = (t == 0) ? 0 : ps[t - 1];
    for (int k = 0; k < ITEMS; ++k) {
        const int s = s0 + k;
        if (s < SCAN_N) {
            const int addr = (s & (R_REP - 1)) * NB + (s >> 5);
            const int c = cnt[addr];
            cnt[addr] = run;
            if ((s & (R_REP - 1)) == 0) boff[s >> 5] = run;
            run += c;
        }
    }
    if (t == 1023) boff[NB] = ps[1023];
}

// ---------------------------------------------------------------------------
// Bucket scatter: 4 edges/thread; claim slot in (bucket, replica) segment,
// store packed (key = local_row<<19 | col, val). Active write frontier is
// NB*R_REP segments (~9 MB) -> L2 merges lines -> full-line HBM writes.
// ---------------------------------------------------------------------------
__global__ __launch_bounds__(256) void bscatter_kernel(
    const int*   __restrict__ A_row,
    const int*   __restrict__ A_col,
    const float* __restrict__ A_val,
    int*  __restrict__ cur,
    int2* __restrict__ epack)
{
    const int e0 = (blockIdx.x * 256 + threadIdx.x) * 4;
    if (e0 >= N_EDGES) return;
    int* c = cur + (blockIdx.x & (R_REP - 1)) * NB;
    const int4   r = *reinterpret_cast<const int4*>(A_row + e0);
    const int4   cc = *reinterpret_cast<const int4*>(A_col + e0);
    const float4 v = *reinterpret_cast<const float4*>(A_val + e0);

    const int p0 = atomicAdd(&c[r.x >> 6], 1);
    const int p1 = atomicAdd(&c[r.y >> 6], 1);
    const int p2 = atomicAdd(&c[r.z >> 6], 1);
    const int p3 = atomicAdd(&c[r.w >> 6], 1);

    epack[p0] = make_int2(((r.x & 63) << 19) | cc.x, __float_as_int(v.x));
    epack[p1] = make_int2(((r.y & 63) << 19) | cc.y, __float_as_int(v.y));
    epack[p2] = make_int2(((r.z & 63) << 19) | cc.z, __float_as_int(v.z));
    epack[p3] = make_int2(((r.w & 63) << 19) | cc.w, __float_as_int(v.w));
}

// ---------------------------------------------------------------------------
// Bucket pull: one block per bucket; 64x64 fp32 accumulator tile in LDS
// (init = identity residual). 4 waves split the bucket's edges; per edge:
// gather trans[col] (128B, coalesced, L2/L3-hot) and LDS-atomic-add into
// acc[local_row][lane] (wave-uniform row -> 2-way bank alias = free).
// Coalesced fp32 store of the tile. No global fp32 atomics anywhere.
// ---------------------------------------------------------------------------
__global__ __launch_bounds__(256) void bucket_pull_kernel(
    const int*    __restrict__ boff,
    const int2*   __restrict__ epack,
    const __half* __restrict__ trans,
    const float*  __restrict__ user_feat,
    const float*  __restrict__ item_feat,
    float* __restrict__ out)
{
    __shared__ float acc[RPB][D];   // 16 KB
    const int b    = blockIdx.x;
    const int r0   = b * RPB;
    const int t    = threadIdx.x;
    const int lane = t & 63;
    const int wv   = t >> 6;        // 0..3

    // init with identity residual
    #pragma unroll
    for (int k = 0; k < RPB / 4; ++k) {
        const int lr = k * 4 + wv;
        const int r  = r0 + lr;
        if (r < N_TOTAL) {
            const float* fp = (r < N_USERS)
                ? user_feat + (size_t)r * D
                : item_feat + (size_t)(r - N_USERS) * D;
            acc[lr][lane] = fp[lane];
        }
    }
    __syncthreads();

    const int s = boff[b], e = boff[b + 1];
    const int per = (e - s + 3) >> 2;
    const int ws  = s + wv * per;
    const int we  = min(ws + per, e);

    int i = ws;
    for (; i + 8 <= we; i += 8) {
        int2 p[8];
        #pragma unroll
        for (int u = 0; u < 8; ++u) p[u] = epack[i + u];
        float tv[8];
        #pragma unroll
        for (int u = 0; u < 8; ++u)
            tv[u] = __half2float(trans[((p[u].x & 0x7FFFF) << 6) | lane]);
        #pragma unroll
        for (int u = 0; u < 8; ++u)
            atomicAdd(&acc[p[u].x >> 19][lane], __int_as_float(p[u].y) * tv[u]);
    }
    for (; i < we; ++i) {
        const int2 p = epack[i];
        const float tv = __half2float(trans[((p.x & 0x7FFFF) << 6) | lane]);
        atomicAdd(&acc[p.x >> 19][lane], __int_as_float(p.y) * tv);
    }
    __syncthreads();

    #pragma unroll
    for (int k = 0; k < RPB / 4; ++k) {
        const int lr = k * 4 + wv;
        const int r  = r0 + lr;
        if (r < N_TOTAL) out[(size_t)r * D + lane] = acc[lr][lane];
    }
}

// ---------------------------------------------------------------------------
// Fallback kernels (small workspace): atomic push path (passed in R1).
// ---------------------------------------------------------------------------
__global__ __launch_bounds__(256) void linear_kernel(
    const float* __restrict__ user_feat,
    const float* __restrict__ item_feat,
    const float* __restrict__ W,
    const float* __restrict__ b,
    float* __restrict__ trans,
    float* __restrict__ out)
{
    __shared__ float Ws[D][D + 1];
    __shared__ float bs[D];
    const int t = threadIdx.x;
    for (int i = t; i < D * D; i += 256) Ws[i >> 6][i & 63] = W[i];
    if (t < D) bs[t] = b[t];
    __syncthreads();

    const int lane = t & 63;
    const int row  = blockIdx.x * 4 + (t >> 6);
    if (row >= N_TOTAL) return;

    const float* feat = (row < N_USERS)
        ? user_feat + (size_t)row * D
        : item_feat + (size_t)(row - N_USERS) * D;

    const float fv = feat[lane];
    float acc = bs[lane];
    #pragma unroll
    for (int k = 0; k < D; ++k)
        acc = fmaf(__shfl(fv, k, 64), Ws[lane][k], acc);

    const size_t off = (size_t)row * D + lane;
    trans[off] = acc;
    if (out) out[off] = fv;
}

__global__ __launch_bounds__(256) void edge_scatter_kernel(
    const int*   __restrict__ A_row,
    const int*   __restrict__ A_col,
    const float* __restrict__ A_val,
    const float* __restrict__ trans,
    float*       __restrict__ out)
{
    const int lane = threadIdx.x & 63;
    const long long e = ((long long)blockIdx.x * 256 + threadIdx.x) >> 6;
    if (e >= N_EDGES) return;
    atomicAdd(out + (size_t)A_row[e] * D + lane,
              A_val[e] * trans[(size_t)A_col[e] * D + lane]);
}

__global__ __launch_bounds__(256) void init_out_kernel(
    const float* __restrict__ user_feat,
    const float* __restrict__ item_feat,
    float* __restrict__ out)
{
    const size_t i = (size_t)blockIdx.x * 256 + threadIdx.x;
    if (i >= (size_t)N_TOTAL * D) return;
    const size_t urows = (size_t)N_USERS * D;
    out[i] = (i < urows) ? user_feat[i] : item_feat[i - urows];
}

__global__ __launch_bounds__(256) void fused_edge_kernel(
    const int*   __restrict__ A_row,
    const int*   __restrict__ A_col,
    const float* __restrict__ A_val,
    const float* __restrict__ user_feat,
    const float* __restrict__ item_feat,
    const float* __restrict__ W,
    const float* __restrict__ b,
    float*       __restrict__ out)
{
    __shared__ float Ws[D][D + 1];
    __shared__ float bs[D];
    const int t = threadIdx.x;
    for (int i = t; i < D * D; i += 256) Ws[i >> 6][i & 63] = W[i];
    if (t < D) bs[t] = b[t];
    __syncthreads();

    const int lane = t & 63;
    const long long e = ((long long)blockIdx.x * 256 + t) >> 6;
    if (e >= N_EDGES) return;

    const int   r = A_row[e];
    const int   c = A_col[e];
    const float v = A_val[e];

    const float* feat = (c < N_USERS)
        ? user_feat + (size_t)c * D
        : item_feat + (size_t)(c - N_USERS) * D;

    const float fv = feat[lane];
    float acc = bs[lane];
    #pragma unroll
    for (int k = 0; k < D; ++k)
        acc = fmaf(__shfl(fv, k, 64), Ws[lane][k], acc);

    atomicAdd(out + (size_t)r * D + lane, v * acc);
}

// ---------------------------------------------------------------------------
extern "C" void kernel_launch(void* const* d_in, const int* in_sizes, int n_in,
                              void* d_out, int out_size, void* d_ws, size_t ws_size,
                              hipStream_t stream)
{
    const int*   A_row     = (const int*)  d_in[0];
    const int*   A_col     = (const int*)  d_in[1];
    const float* A_val     = (const float*)d_in[2];
    const float* user_feat = (const float*)d_in[3];
    const float* item_feat = (const float*)d_in[4];
    const float* W         = (const float*)d_in[5];
    const float* b         = (const float*)d_in[6];
    float*       out       = (float*)d_out;

    const size_t a256 = 255;
    const size_t transh_bytes = (((size_t)N_TOTAL * D * sizeof(__half)) + a256) & ~a256; // 38.4 MB
    const size_t cnt_bytes    = (((size_t)SCAN_N * sizeof(int)) + a256) & ~a256;         // 600 KB
    const size_t boff_bytes   = (((size_t)(NB + 1) * sizeof(int)) + a256) & ~a256;       // 18.8 KB
    const size_t epack_bytes  = (size_t)N_EDGES * sizeof(int2);                          // 48 MB
    const size_t main_total   = transh_bytes + cnt_bytes + boff_bytes + epack_bytes;     // ~87 MB

    const size_t trans_bytes  = (size_t)N_TOTAL * D * sizeof(float);                     // 76.8 MB (fallback)

    const int row_blocks  = (N_TOTAL + 3) / 4;
    const int quad_blocks = (N_EDGES / 4 + 255) / 256;

    if (ws_size >= main_total) {
        char* p = (char*)d_ws;
        __half* transh = (__half*)p;  p += transh_bytes;
        int*    cnt    = (int*)p;     p += cnt_bytes;
        int*    boff   = (int*)p;     p += boff_bytes;
        int2*   epack  = (int2*)p;

        hipMemsetAsync(cnt, 0, (size_t)SCAN_N * sizeof(int), stream);
        linear_half_kernel<<<row_blocks, 256, 0, stream>>>(
            user_feat, item_feat, W, b, transh);
        bhist_kernel<<<quad_blocks, 256, 0, stream>>>(A_row, cnt);
        bscan_kernel<<<1, 1024, 0, stream>>>(cnt, boff);
        bscatter_kernel<<<quad_blocks, 256, 0, stream>>>(
            A_row, A_col, A_val, cnt, epack);
        bucket_pull_kernel<<<NB, 256, 0, stream>>>(
            boff, epack, transh, user_feat, item_feat, out);
    } else if (ws_size >= trans_bytes) {
        float* trans = (float*)d_ws;
        linear_kernel<<<row_blocks, 256, 0, stream>>>(
            user_feat, item_feat, W, b, trans, out);
        edge_scatter_kernel<<<N_EDGES / 4, 256, 0, stream>>>(
            A_row, A_col, A_val, trans, out);
    } else {
        const size_t total = (size_t)N_TOTAL * D;
        init_out_kernel<<<(int)((total + 255) / 256), 256, 0, stream>>>(
            user_feat, item_feat, out);
        fused_edge_kernel<<<N_EDGES / 4, 256, 0, stream>>>(
            A_row, A_col, A_val, user_feat, item_feat, W, b, out);
    }
}

// Round 6
// 1077.214 us; speedup vs baseline: 2.7930x; 2.7930x over previous
//
#include <hip/hip_runtime.h>
#include <hip/hip_fp16.h>

#define N_USERS 100000
#define N_ITEMS 200000
#define N_TOTAL 300000
#define N_EDGES 6000000
#define D 64

#define SCAN_THREADS 256
#define SCAN_ITEMS 4
#define SCAN_TILE (SCAN_THREADS * SCAN_ITEMS)             // 1024
#define SCAN_NBLK ((N_TOTAL + SCAN_TILE - 1) / SCAN_TILE) // 293

#define NRANGE 16
#define ROWS_PER_RANGE (N_TOTAL / NRANGE)                 // 18750 (exact)
#define CHUNK 1024                                        // edges per block
#define NCB ((N_EDGES + CHUNK - 1) / CHUNK)               // 5860

// ---------------------------------------------------------------------------
// trans(fp16) = all_feat @ W^T + b  (one wave per row). fp16 halves pull's
// gather traffic; |trans| small so fp16 error ~5e-3 << 0.595 (R5 passed).
// ---------------------------------------------------------------------------
__global__ __launch_bounds__(256) void linear_half_kernel(
    const float* __restrict__ user_feat,
    const float* __restrict__ item_feat,
    const float* __restrict__ W,
    const float* __restrict__ b,
    __half* __restrict__ trans)
{
    __shared__ float Ws[D][D + 1];
    __shared__ float bs[D];
    const int t = threadIdx.x;
    for (int i = t; i < D * D; i += 256) Ws[i >> 6][i & 63] = W[i];
    if (t < D) bs[t] = b[t];
    __syncthreads();

    const int lane = t & 63;
    const int row  = blockIdx.x * 4 + (t >> 6);
    if (row >= N_TOTAL) return;

    const float* feat = (row < N_USERS)
        ? user_feat + (size_t)row * D
        : item_feat + (size_t)(row - N_USERS) * D;

    const float fv = feat[lane];
    float acc = bs[lane];
    #pragma unroll
    for (int k = 0; k < D; ++k)
        acc = fmaf(__shfl(fv, k, 64), Ws[lane][k], acc);

    trans[(size_t)row * D + lane] = __float2half(acc);
}

// ---------------------------------------------------------------------------
// Histogram: 4 edges/thread, compact counters (1.2 MB).
// ---------------------------------------------------------------------------
__global__ __launch_bounds__(256) void hist_kernel(
    const int* __restrict__ A_row, int* __restrict__ rowoff)
{
    const int e0 = (blockIdx.x * 256 + threadIdx.x) * 4;
    if (e0 >= N_EDGES) return;
    const int4 r = *reinterpret_cast<const int4*>(A_row + e0);
    atomicAdd(&rowoff[r.x], 1);
    atomicAdd(&rowoff[r.y], 1);
    atomicAdd(&rowoff[r.z], 1);
    atomicAdd(&rowoff[r.w], 1);
}

// ---------------------------------------------------------------------------
// Exclusive scan over rowoff (in place).
// ---------------------------------------------------------------------------
__global__ __launch_bounds__(SCAN_THREADS) void scan_block_kernel(
    int* __restrict__ rowoff, int* __restrict__ bsum)
{
    __shared__ int s[SCAN_THREADS];
    const int t    = threadIdx.x;
    const int base = blockIdx.x * SCAN_TILE + t * SCAN_ITEMS;

    int v[SCAN_ITEMS];
    int sum = 0;
    #pragma unroll
    for (int i = 0; i < SCAN_ITEMS; ++i) {
        const int idx = base + i;
        v[i] = (idx < N_TOTAL) ? rowoff[idx] : 0;
        sum += v[i];
    }
    s[t] = sum;
    __syncthreads();
    for (int d = 1; d < SCAN_THREADS; d <<= 1) {
        const int x = (t >= d) ? s[t - d] : 0;
        __syncthreads();
        s[t] += x;
        __syncthreads();
    }
    int run = (t == 0) ? 0 : s[t - 1];
    #pragma unroll
    for (int i = 0; i < SCAN_ITEMS; ++i) {
        const int idx = base + i;
        if (idx < N_TOTAL) rowoff[idx] = run;
        run += v[i];
    }
    if (t == SCAN_THREADS - 1) bsum[blockIdx.x] = s[t];
}

__global__ __launch_bounds__(512) void scan_sums_kernel(int* __restrict__ bsum)
{
    __shared__ int s[512];
    const int t = threadIdx.x;
    s[t] = (t < SCAN_NBLK) ? bsum[t] : 0;
    __syncthreads();
    for (int d = 1; d < 512; d <<= 1) {
        const int x = (t >= d) ? s[t - d] : 0;
        __syncthreads();
        s[t] += x;
        __syncthreads();
    }
    if (t < SCAN_NBLK) bsum[t] = (t == 0) ? 0 : s[t - 1];
}

__global__ __launch_bounds__(256) void scan_add_kernel(
    int* __restrict__ rowoff, const int* __restrict__ bsum)
{
    const int i = blockIdx.x * 256 + threadIdx.x;
    if (i < N_TOTAL) rowoff[i] += bsum[i / SCAN_TILE];
}

// ---------------------------------------------------------------------------
// Range-filtered scatter. Grid = 2 phases x 8 x NCB. range = (b&7)+8*phase:
// with round-robin block->XCD dispatch, range r's blocks run on XCD r&7, and
// phase 1 dispatches after phase 0 drains. Each range owns 18750 rows ->
// 3 MB epack region + 75 KB cursors, L2-resident on its XCD -> stores merge
// into full lines (kills the 64B-line write amplification). A_row is scanned
// 16x but L3-broadcast. After this kernel rowoff[r] == end of row r.
// ---------------------------------------------------------------------------
__global__ __launch_bounds__(256) void range_scatter_kernel(
    const int*   __restrict__ A_row,
    const int*   __restrict__ A_col,
    const float* __restrict__ A_val,
    int*  __restrict__ rowoff,
    int2* __restrict__ epack)
{
    const int b     = blockIdx.x;
    const int r7    = b & 7;
    const int g     = b >> 3;                 // 0 .. 2*NCB-1
    const int phase = (g >= NCB) ? 1 : 0;
    const int chunk = g - phase * NCB;
    const int range = r7 + (phase << 3);
    const int lo    = range * ROWS_PER_RANGE;
    const int hi    = lo + ROWS_PER_RANGE;

    const int e0 = chunk * CHUNK + threadIdx.x * 4;
    if (e0 >= N_EDGES) return;
    const int4 r = *reinterpret_cast<const int4*>(A_row + e0);

    if (r.x >= lo && r.x < hi) {
        const int p = atomicAdd(&rowoff[r.x], 1);
        epack[p] = make_int2(A_col[e0], __float_as_int(A_val[e0]));
    }
    if (r.y >= lo && r.y < hi) {
        const int p = atomicAdd(&rowoff[r.y], 1);
        epack[p] = make_int2(A_col[e0 + 1], __float_as_int(A_val[e0 + 1]));
    }
    if (r.z >= lo && r.z < hi) {
        const int p = atomicAdd(&rowoff[r.z], 1);
        epack[p] = make_int2(A_col[e0 + 2], __float_as_int(A_val[e0 + 2]));
    }
    if (r.w >= lo && r.w < hi) {
        const int p = atomicAdd(&rowoff[r.w], 1);
        epack[p] = make_int2(A_col[e0 + 3], __float_as_int(A_val[e0 + 3]));
    }
}

// ---------------------------------------------------------------------------
// Pull: one wave per row, lane = column. 8-wide unroll; fp16 trans gathers
// (128B/edge, fully consumed). Register accumulation -> no atomics at all.
// ---------------------------------------------------------------------------
__global__ __launch_bounds__(256) void pull_half_kernel(
    const int*    __restrict__ rowoff,
    const int2*   __restrict__ epack,
    const __half* __restrict__ trans,
    const float*  __restrict__ user_feat,
    const float*  __restrict__ item_feat,
    float* __restrict__ out)
{
    const int lane = threadIdx.x & 63;
    const int row  = blockIdx.x * 4 + (threadIdx.x >> 6);
    if (row >= N_TOTAL) return;

    const float* feat = (row < N_USERS)
        ? user_feat + (size_t)row * D
        : item_feat + (size_t)(row - N_USERS) * D;

    float a0 = feat[lane];            // identity residual
    float a1 = 0.f, a2 = 0.f, a3 = 0.f, a4 = 0.f, a5 = 0.f, a6 = 0.f, a7 = 0.f;

    const int s   = (row == 0) ? 0 : rowoff[row - 1];
    const int end = rowoff[row];

    int i = s;
    for (; i + 7 < end; i += 8) {
        const int2 p0 = epack[i    ], p1 = epack[i + 1];
        const int2 p2 = epack[i + 2], p3 = epack[i + 3];
        const int2 p4 = epack[i + 4], p5 = epack[i + 5];
        const int2 p6 = epack[i + 6], p7 = epack[i + 7];
        const float t0 = __half2float(trans[((size_t)p0.x << 6) | lane]);
        const float t1 = __half2float(trans[((size_t)p1.x << 6) | lane]);
        const float t2 = __half2float(trans[((size_t)p2.x << 6) | lane]);
        const float t3 = __half2float(trans[((size_t)p3.x << 6) | lane]);
        const float t4 = __half2float(trans[((size_t)p4.x << 6) | lane]);
        const float t5 = __half2float(trans[((size_t)p5.x << 6) | lane]);
        const float t6 = __half2float(trans[((size_t)p6.x << 6) | lane]);
        const float t7 = __half2float(trans[((size_t)p7.x << 6) | lane]);
        a0 = fmaf(__int_as_float(p0.y), t0, a0);
        a1 = fmaf(__int_as_float(p1.y), t1, a1);
        a2 = fmaf(__int_as_float(p2.y), t2, a2);
        a3 = fmaf(__int_as_float(p3.y), t3, a3);
        a4 = fmaf(__int_as_float(p4.y), t4, a4);
        a5 = fmaf(__int_as_float(p5.y), t5, a5);
        a6 = fmaf(__int_as_float(p6.y), t6, a6);
        a7 = fmaf(__int_as_float(p7.y), t7, a7);
    }
    for (; i < end; ++i) {
        const int2 p = epack[i];
        a0 = fmaf(__int_as_float(p.y),
                  __half2float(trans[((size_t)p.x << 6) | lane]), a0);
    }
    out[(size_t)row * D + lane] = ((a0 + a1) + (a2 + a3)) + ((a4 + a5) + (a6 + a7));
}

// ---------------------------------------------------------------------------
// Fallback kernels (small workspace): atomic push path (passed in R1).
// ---------------------------------------------------------------------------
__global__ __launch_bounds__(256) void linear_kernel(
    const float* __restrict__ user_feat,
    const float* __restrict__ item_feat,
    const float* __restrict__ W,
    const float* __restrict__ b,
    float* __restrict__ trans,
    float* __restrict__ out)
{
    __shared__ float Ws[D][D + 1];
    __shared__ float bs[D];
    const int t = threadIdx.x;
    for (int i = t; i < D * D; i += 256) Ws[i >> 6][i & 63] = W[i];
    if (t < D) bs[t] = b[t];
    __syncthreads();

    const int lane = t & 63;
    const int row  = blockIdx.x * 4 + (t >> 6);
    if (row >= N_TOTAL) return;

    const float* feat = (row < N_USERS)
        ? user_feat + (size_t)row * D
        : item_feat + (size_t)(row - N_USERS) * D;

    const float fv = feat[lane];
    float acc = bs[lane];
    #pragma unroll
    for (int k = 0; k < D; ++k)
        acc = fmaf(__shfl(fv, k, 64), Ws[lane][k], acc);

    const size_t off = (size_t)row * D + lane;
    trans[off] = acc;
    if (out) out[off] = fv;
}

__global__ __launch_bounds__(256) void edge_scatter_kernel(
    const int*   __restrict__ A_row,
    const int*   __restrict__ A_col,
    const float* __restrict__ A_val,
    const float* __restrict__ trans,
    float*       __restrict__ out)
{
    const int lane = threadIdx.x & 63;
    const long long e = ((long long)blockIdx.x * 256 + threadIdx.x) >> 6;
    if (e >= N_EDGES) return;
    atomicAdd(out + (size_t)A_row[e] * D + lane,
              A_val[e] * trans[(size_t)A_col[e] * D + lane]);
}

__global__ __launch_bounds__(256) void init_out_kernel(
    const float* __restrict__ user_feat,
    const float* __restrict__ item_feat,
    float* __restrict__ out)
{
    const size_t i = (size_t)blockIdx.x * 256 + threadIdx.x;
    if (i >= (size_t)N_TOTAL * D) return;
    const size_t urows = (size_t)N_USERS * D;
    out[i] = (i < urows) ? user_feat[i] : item_feat[i - urows];
}

__global__ __launch_bounds__(256) void fused_edge_kernel(
    const int*   __restrict__ A_row,
    const int*   __restrict__ A_col,
    const float* __restrict__ A_val,
    const float* __restrict__ user_feat,
    const float* __restrict__ item_feat,
    const float* __restrict__ W,
    const float* __restrict__ b,
    float*       __restrict__ out)
{
    __shared__ float Ws[D][D + 1];
    __shared__ float bs[D];
    const int t = threadIdx.x;
    for (int i = t; i < D * D; i += 256) Ws[i >> 6][i & 63] = W[i];
    if (t < D) bs[t] = b[t];
    __syncthreads();

    const int lane = t & 63;
    const long long e = ((long long)blockIdx.x * 256 + t) >> 6;
    if (e >= N_EDGES) return;

    const int   r = A_row[e];
    const int   c = A_col[e];
    const float v = A_val[e];

    const float* feat = (c < N_USERS)
        ? user_feat + (size_t)c * D
        : item_feat + (size_t)(c - N_USERS) * D;

    const float fv = feat[lane];
    float acc = bs[lane];
    #pragma unroll
    for (int k = 0; k < D; ++k)
        acc = fmaf(__shfl(fv, k, 64), Ws[lane][k], acc);

    atomicAdd(out + (size_t)r * D + lane, v * acc);
}

// ---------------------------------------------------------------------------
extern "C" void kernel_launch(void* const* d_in, const int* in_sizes, int n_in,
                              void* d_out, int out_size, void* d_ws, size_t ws_size,
                              hipStream_t stream)
{
    const int*   A_row     = (const int*)  d_in[0];
    const int*   A_col     = (const int*)  d_in[1];
    const float* A_val     = (const float*)d_in[2];
    const float* user_feat = (const float*)d_in[3];
    const float* item_feat = (const float*)d_in[4];
    const float* W         = (const float*)d_in[5];
    const float* b         = (const float*)d_in[6];
    float*       out       = (float*)d_out;

    const size_t a256 = 255;
    const size_t transh_bytes = (((size_t)N_TOTAL * D * sizeof(__half)) + a256) & ~a256; // 38.4 MB
    const size_t rowoff_bytes = (((size_t)N_TOTAL * sizeof(int)) + a256) & ~a256;        // 1.2 MB
    const size_t bsum_bytes   = (((size_t)SCAN_NBLK * sizeof(int)) + a256) & ~a256;
    const size_t epack_bytes  = (size_t)N_EDGES * sizeof(int2);                          // 48 MB
    const size_t main_total   = transh_bytes + rowoff_bytes + bsum_bytes + epack_bytes;  // ~87.6 MB

    const size_t trans_bytes  = (size_t)N_TOTAL * D * sizeof(float);                     // fallback

    const int row_blocks  = (N_TOTAL + 3) / 4;
    const int quad_blocks = (N_EDGES / 4 + 255) / 256;

    if (ws_size >= main_total) {
        char* p = (char*)d_ws;
        __half* transh = (__half*)p;  p += transh_bytes;
        int*    rowoff = (int*)p;     p += rowoff_bytes;
        int*    bsum   = (int*)p;     p += bsum_bytes;
        int2*   epack  = (int2*)p;

        hipMemsetAsync(rowoff, 0, (size_t)N_TOTAL * sizeof(int), stream);
        linear_half_kernel<<<row_blocks, 256, 0, stream>>>(
            user_feat, item_feat, W, b, transh);
        hist_kernel<<<quad_blocks, 256, 0, stream>>>(A_row, rowoff);
        scan_block_kernel<<<SCAN_NBLK, SCAN_THREADS, 0, stream>>>(rowoff, bsum);
        scan_sums_kernel<<<1, 512, 0, stream>>>(bsum);
        scan_add_kernel<<<(N_TOTAL + 255) / 256, 256, 0, stream>>>(rowoff, bsum);
        range_scatter_kernel<<<2 * 8 * NCB, 256, 0, stream>>>(
            A_row, A_col, A_val, rowoff, epack);
        pull_half_kernel<<<row_blocks, 256, 0, stream>>>(
            rowoff, epack, transh, user_feat, item_feat, out);
    } else if (ws_size >= trans_bytes) {
        float* trans = (float*)d_ws;
        linear_kernel<<<row_blocks, 256, 0, stream>>>(
            user_feat, item_feat, W, b, trans, out);
        edge_scatter_kernel<<<N_EDGES / 4, 256, 0, stream>>>(
            A_row, A_col, A_val, trans, out);
    } else {
        const size_t total = (size_t)N_TOTAL * D;
        init_out_kernel<<<(int)((total + 255) / 256), 256, 0, stream>>>(
            user_feat, item_feat, out);
        fused_edge_kernel<<<N_EDGES / 4, 256, 0, stream>>>(
            A_row, A_col, A_val, user_feat, item_feat, W, b, out);
    }
}

// Round 7
// 731.537 us; speedup vs baseline: 4.1128x; 1.4725x over previous
//
#include <hip/hip_runtime.h>
#include <hip/hip_fp16.h>

#define N_USERS 100000
#define N_ITEMS 200000
#define N_TOTAL 300000
#define N_EDGES 6000000
#define D 64

#define BSHIFT 10
#define BROWS 1024                                // rows per bucket
#define NBUCK ((N_TOTAL + BROWS - 1) / BROWS)     // 293
#define EPB 4096                                  // edges per partition block
#define NPB ((N_EDGES + EPB - 1) / EPB)           // 1465

typedef float    f32x4 __attribute__((ext_vector_type(4)));
typedef _Float16 f16x8 __attribute__((ext_vector_type(8)));

// ---------------------------------------------------------------------------
// Linear via MFMA: trans(fp16) = all_feat @ W^T + b.
// Block = 64 rows, 4 waves x 16 rows. Wave holds W as 8 B-fragments in regs
// (4 col-tiles x 2 k-frags), loads its A-fragments once, 8 MFMAs.
// Layouts (m89-verified): A/B: idx=lane&15, k=(lane>>4)*8+j;
//                         C/D: col=lane&15, row=(lane>>4)*4+reg.
// ---------------------------------------------------------------------------
__global__ __launch_bounds__(256) void linear_mfma_kernel(
    const float* __restrict__ user_feat,
    const float* __restrict__ item_feat,
    const float* __restrict__ W,
    const float* __restrict__ bias,
    __half* __restrict__ trans)
{
    const int lane = threadIdx.x & 63;
    const int wv   = threadIdx.x >> 6;
    const int r0   = blockIdx.x * 64 + wv * 16;
    const int arow = lane & 15;
    const int kg   = lane >> 4;                   // 0..3

    // B fragments: W[c][k], c = ct*16+arow, k = kf*32 + kg*8 + j
    f16x8 wf[4][2];
    #pragma unroll
    for (int ct = 0; ct < 4; ++ct) {
        const float* wp = W + (size_t)(ct * 16 + arow) * D;
        #pragma unroll
        for (int kf = 0; kf < 2; ++kf) {
            const int k0 = kf * 32 + kg * 8;
            const float4 w0 = *reinterpret_cast<const float4*>(wp + k0);
            const float4 w1 = *reinterpret_cast<const float4*>(wp + k0 + 4);
            f16x8 h;
            h[0] = (_Float16)w0.x; h[1] = (_Float16)w0.y;
            h[2] = (_Float16)w0.z; h[3] = (_Float16)w0.w;
            h[4] = (_Float16)w1.x; h[5] = (_Float16)w1.y;
            h[6] = (_Float16)w1.z; h[7] = (_Float16)w1.w;
            wf[ct][kf] = h;
        }
    }

    // A fragments: row = r0+arow (clamped for tail block), same k mapping
    int rr = r0 + arow;
    if (rr >= N_TOTAL) rr = N_TOTAL - 1;
    const float* fp = (rr < N_USERS) ? user_feat + (size_t)rr * D
                                     : item_feat + (size_t)(rr - N_USERS) * D;
    f16x8 af[2];
    #pragma unroll
    for (int kf = 0; kf < 2; ++kf) {
        const int k0 = kf * 32 + kg * 8;
        const float4 a0 = *reinterpret_cast<const float4*>(fp + k0);
        const float4 a1 = *reinterpret_cast<const float4*>(fp + k0 + 4);
        f16x8 h;
        h[0] = (_Float16)a0.x; h[1] = (_Float16)a0.y;
        h[2] = (_Float16)a0.z; h[3] = (_Float16)a0.w;
        h[4] = (_Float16)a1.x; h[5] = (_Float16)a1.y;
        h[6] = (_Float16)a1.z; h[7] = (_Float16)a1.w;
        af[kf] = h;
    }

    #pragma unroll
    for (int ct = 0; ct < 4; ++ct) {
        const float bc = bias[ct * 16 + arow];
        f32x4 acc = {bc, bc, bc, bc};
        acc = __builtin_amdgcn_mfma_f32_16x16x32_f16(af[0], wf[ct][0], acc, 0, 0, 0);
        acc = __builtin_amdgcn_mfma_f32_16x16x32_f16(af[1], wf[ct][1], acc, 0, 0, 0);
        #pragma unroll
        for (int reg = 0; reg < 4; ++reg) {
            const int ro = r0 + kg * 4 + reg;
            if (ro < N_TOTAL)
                trans[(size_t)ro * D + ct * 16 + arow] = __float2half(acc[reg]);
        }
    }
}

// ---------------------------------------------------------------------------
// Bucket histogram: per-block LDS counts, one global atomic per bucket.
// ---------------------------------------------------------------------------
__global__ __launch_bounds__(256) void bucket_hist_kernel(
    const int* __restrict__ A_row, int* __restrict__ gbcnt)
{
    __shared__ int lcnt[NBUCK];
    for (int i = threadIdx.x; i < NBUCK; i += 256) lcnt[i] = 0;
    __syncthreads();
    const int base = blockIdx.x * EPB;
    #pragma unroll
    for (int j = 0; j < 4; ++j) {
        const int e0 = base + j * 1024 + threadIdx.x * 4;
        if (e0 < N_EDGES) {
            const int4 r = *reinterpret_cast<const int4*>(A_row + e0);
            atomicAdd(&lcnt[r.x >> BSHIFT], 1);
            atomicAdd(&lcnt[r.y >> BSHIFT], 1);
            atomicAdd(&lcnt[r.z >> BSHIFT], 1);
            atomicAdd(&lcnt[r.w >> BSHIFT], 1);
        }
    }
    __syncthreads();
    for (int i = threadIdx.x; i < NBUCK; i += 256)
        if (lcnt[i]) atomicAdd(&gbcnt[i], lcnt[i]);
}

// ---------------------------------------------------------------------------
// Exclusive scan over NBUCK bucket counts -> boff (starts) and gcur (cursors).
// ---------------------------------------------------------------------------
__global__ __launch_bounds__(512) void bucket_scan_kernel(
    const int* __restrict__ gbcnt, int* __restrict__ boff, int* __restrict__ gcur)
{
    __shared__ int s[512];
    const int t = threadIdx.x;
    s[t] = (t < NBUCK) ? gbcnt[t] : 0;
    __syncthreads();
    for (int d2 = 1; d2 < 512; d2 <<= 1) {
        const int x = (t >= d2) ? s[t - d2] : 0;
        __syncthreads();
        s[t] += x;
        __syncthreads();
    }
    if (t < NBUCK) {
        const int excl = (t == 0) ? 0 : s[t - 1];
        boff[t] = excl;
        gcur[t] = excl;
    }
    if (t == 0) boff[NBUCK] = N_EDGES;
}

// ---------------------------------------------------------------------------
// Pass 1: 293-way partition of edge ids. LDS-claimed local positions + one
// global cursor atomic per (block,bucket) -> eids written in contiguous runs.
// ---------------------------------------------------------------------------
__global__ __launch_bounds__(256) void partition_kernel(
    const int* __restrict__ A_row,
    int* __restrict__ gcur,
    int* __restrict__ eids)
{
    __shared__ int lcnt[NBUCK];
    __shared__ int gb[NBUCK];
    for (int i = threadIdx.x; i < NBUCK; i += 256) lcnt[i] = 0;
    __syncthreads();

    const int base = blockIdx.x * EPB;
    int pk[16];
    #pragma unroll
    for (int j = 0; j < 4; ++j) {
        const int e0 = base + j * 1024 + threadIdx.x * 4;
        if (e0 < N_EDGES) {
            const int4 r = *reinterpret_cast<const int4*>(A_row + e0);
            pk[4*j+0] = ((r.x >> BSHIFT) << 13) | atomicAdd(&lcnt[r.x >> BSHIFT], 1);
            pk[4*j+1] = ((r.y >> BSHIFT) << 13) | atomicAdd(&lcnt[r.y >> BSHIFT], 1);
            pk[4*j+2] = ((r.z >> BSHIFT) << 13) | atomicAdd(&lcnt[r.z >> BSHIFT], 1);
            pk[4*j+3] = ((r.w >> BSHIFT) << 13) | atomicAdd(&lcnt[r.w >> BSHIFT], 1);
        }
    }
    __syncthreads();
    for (int i = threadIdx.x; i < NBUCK; i += 256)
        gb[i] = lcnt[i] ? atomicAdd(&gcur[i], lcnt[i]) : 0;
    __syncthreads();

    #pragma unroll
    for (int j = 0; j < 4; ++j) {
        const int e0 = base + j * 1024 + threadIdx.x * 4;
        if (e0 < N_EDGES) {
            #pragma unroll
            for (int q = 0; q < 4; ++q) {
                const int p = pk[4*j+q];
                eids[gb[p >> 13] + (p & 0x1FFF)] = e0 + q;
            }
        }
    }
}

// ---------------------------------------------------------------------------
// Pass 2: one block per bucket. Row-CSR built entirely in LDS (count -> scan
// -> claim); (col,val) written into the bucket's private 164 KB region by a
// single block in one window -> L2 merges into full lines. Also emits
// rowoff[row] = end-of-row (replaces global hist + 300K scan).
// ---------------------------------------------------------------------------
__global__ __launch_bounds__(256) void bucket_csr_kernel(
    const int*   __restrict__ boff,
    const int*   __restrict__ eids,
    const int*   __restrict__ A_row,
    const int*   __restrict__ A_col,
    const float* __restrict__ A_val,
    int*  __restrict__ rowoff,
    int2* __restrict__ epack)
{
    __shared__ int rcnt[BROWS];
    __shared__ int rcur[BROWS];
    __shared__ int s[256];
    const int b  = blockIdx.x;
    const int t  = threadIdx.x;
    const int s0 = boff[b], s1 = boff[b + 1];

    for (int i = t; i < BROWS; i += 256) rcnt[i] = 0;
    __syncthreads();

    for (int i = s0 + t; i < s1; i += 256)
        atomicAdd(&rcnt[A_row[eids[i]] & (BROWS - 1)], 1);
    __syncthreads();

    // exclusive scan rcnt -> rcur (256 threads x 4 items)
    int v[4]; int sum = 0;
    #pragma unroll
    for (int q = 0; q < 4; ++q) { v[q] = rcnt[t * 4 + q]; sum += v[q]; }
    s[t] = sum;
    __syncthreads();
    for (int d2 = 1; d2 < 256; d2 <<= 1) {
        const int x = (t >= d2) ? s[t - d2] : 0;
        __syncthreads();
        s[t] += x;
        __syncthreads();
    }
    int run = (t == 0) ? 0 : s[t - 1];
    #pragma unroll
    for (int q = 0; q < 4; ++q) { rcur[t * 4 + q] = run; run += v[q]; }
    __syncthreads();

    for (int i = s0 + t; i < s1; i += 256) {
        const int e  = eids[i];
        const int lr = A_row[e] & (BROWS - 1);
        const int p  = s0 + atomicAdd(&rcur[lr], 1);
        epack[p] = make_int2(A_col[e], __float_as_int(A_val[e]));
    }
    __syncthreads();

    const int rbase = b << BSHIFT;
    for (int i = t; i < BROWS; i += 256) {
        const int row = rbase + i;
        if (row < N_TOTAL) rowoff[row] = s0 + rcur[i];   // = end of row
    }
}

// ---------------------------------------------------------------------------
// Pull: one wave per row, lane = column. 8-wide unroll; fp16 trans gathers.
// ---------------------------------------------------------------------------
__global__ __launch_bounds__(256) void pull_half_kernel(
    const int*    __restrict__ rowoff,
    const int2*   __restrict__ epack,
    const __half* __restrict__ trans,
    const float*  __restrict__ user_feat,
    const float*  __restrict__ item_feat,
    float* __restrict__ out)
{
    const int lane = threadIdx.x & 63;
    const int row  = blockIdx.x * 4 + (threadIdx.x >> 6);
    if (row >= N_TOTAL) return;

    const float* feat = (row < N_USERS)
        ? user_feat + (size_t)row * D
        : item_feat + (size_t)(row - N_USERS) * D;

    float a0 = feat[lane];            // identity residual
    float a1 = 0.f, a2 = 0.f, a3 = 0.f, a4 = 0.f, a5 = 0.f, a6 = 0.f, a7 = 0.f;

    const int s   = (row == 0) ? 0 : rowoff[row - 1];
    const int end = rowoff[row];

    int i = s;
    for (; i + 7 < end; i += 8) {
        const int2 p0 = epack[i    ], p1 = epack[i + 1];
        const int2 p2 = epack[i + 2], p3 = epack[i + 3];
        const int2 p4 = epack[i + 4], p5 = epack[i + 5];
        const int2 p6 = epack[i + 6], p7 = epack[i + 7];
        const float t0 = __half2float(trans[((size_t)p0.x << 6) | lane]);
        const float t1 = __half2float(trans[((size_t)p1.x << 6) | lane]);
        const float t2 = __half2float(trans[((size_t)p2.x << 6) | lane]);
        const float t3 = __half2float(trans[((size_t)p3.x << 6) | lane]);
        const float t4 = __half2float(trans[((size_t)p4.x << 6) | lane]);
        const float t5 = __half2float(trans[((size_t)p5.x << 6) | lane]);
        const float t6 = __half2float(trans[((size_t)p6.x << 6) | lane]);
        const float t7 = __half2float(trans[((size_t)p7.x << 6) | lane]);
        a0 = fmaf(__int_as_float(p0.y), t0, a0);
        a1 = fmaf(__int_as_float(p1.y), t1, a1);
        a2 = fmaf(__int_as_float(p2.y), t2, a2);
        a3 = fmaf(__int_as_float(p3.y), t3, a3);
        a4 = fmaf(__int_as_float(p4.y), t4, a4);
        a5 = fmaf(__int_as_float(p5.y), t5, a5);
        a6 = fmaf(__int_as_float(p6.y), t6, a6);
        a7 = fmaf(__int_as_float(p7.y), t7, a7);
    }
    for (; i < end; ++i) {
        const int2 p = epack[i];
        a0 = fmaf(__int_as_float(p.y),
                  __half2float(trans[((size_t)p.x << 6) | lane]), a0);
    }
    out[(size_t)row * D + lane] = ((a0 + a1) + (a2 + a3)) + ((a4 + a5) + (a6 + a7));
}

// ---------------------------------------------------------------------------
// Fallback kernels (small workspace): atomic push path (passed in R1).
// ---------------------------------------------------------------------------
__global__ __launch_bounds__(256) void linear_kernel(
    const float* __restrict__ user_feat,
    const float* __restrict__ item_feat,
    const float* __restrict__ W,
    const float* __restrict__ b,
    float* __restrict__ trans,
    float* __restrict__ out)
{
    __shared__ float Ws[D][D + 1];
    __shared__ float bs[D];
    const int t = threadIdx.x;
    for (int i = t; i < D * D; i += 256) Ws[i >> 6][i & 63] = W[i];
    if (t < D) bs[t] = b[t];
    __syncthreads();

    const int lane = t & 63;
    const int row  = blockIdx.x * 4 + (t >> 6);
    if (row >= N_TOTAL) return;

    const float* feat = (row < N_USERS)
        ? user_feat + (size_t)row * D
        : item_feat + (size_t)(row - N_USERS) * D;

    const float fv = feat[lane];
    float acc = bs[lane];
    #pragma unroll
    for (int k = 0; k < D; ++k)
        acc = fmaf(__shfl(fv, k, 64), Ws[lane][k], acc);

    const size_t off = (size_t)row * D + lane;
    trans[off] = acc;
    if (out) out[off] = fv;
}

__global__ __launch_bounds__(256) void edge_scatter_kernel(
    const int*   __restrict__ A_row,
    const int*   __restrict__ A_col,
    const float* __restrict__ A_val,
    const float* __restrict__ trans,
    float*       __restrict__ out)
{
    const int lane = threadIdx.x & 63;
    const long long e = ((long long)blockIdx.x * 256 + threadIdx.x) >> 6;
    if (e >= N_EDGES) return;
    atomicAdd(out + (size_t)A_row[e] * D + lane,
              A_val[e] * trans[(size_t)A_col[e] * D + lane]);
}

__global__ __launch_bounds__(256) void init_out_kernel(
    const float* __restrict__ user_feat,
    const float* __restrict__ item_feat,
    float* __restrict__ out)
{
    const size_t i = (size_t)blockIdx.x * 256 + threadIdx.x;
    if (i >= (size_t)N_TOTAL * D) return;
    const size_t urows = (size_t)N_USERS * D;
    out[i] = (i < urows) ? user_feat[i] : item_feat[i - urows];
}

__global__ __launch_bounds__(256) void fused_edge_kernel(
    const int*   __restrict__ A_row,
    const int*   __restrict__ A_col,
    const float* __restrict__ A_val,
    const float* __restrict__ user_feat,
    const float* __restrict__ item_feat,
    const float* __restrict__ W,
    const float* __restrict__ b,
    float*       __restrict__ out)
{
    __shared__ float Ws[D][D + 1];
    __shared__ float bs[D];
    const int t = threadIdx.x;
    for (int i = t; i < D * D; i += 256) Ws[i >> 6][i & 63] = W[i];
    if (t < D) bs[t] = b[t];
    __syncthreads();

    const int lane = t & 63;
    const long long e = ((long long)blockIdx.x * 256 + t) >> 6;
    if (e >= N_EDGES) return;

    const int   r = A_row[e];
    const int   c = A_col[e];
    const float v = A_val[e];

    const float* feat = (c < N_USERS)
        ? user_feat + (size_t)c * D
        : item_feat + (size_t)(c - N_USERS) * D;

    const float fv = feat[lane];
    float acc = bs[lane];
    #pragma unroll
    for (int k = 0; k < D; ++k)
        acc = fmaf(__shfl(fv, k, 64), Ws[lane][k], acc);

    atomicAdd(out + (size_t)r * D + lane, v * acc);
}

// ---------------------------------------------------------------------------
extern "C" void kernel_launch(void* const* d_in, const int* in_sizes, int n_in,
                              void* d_out, int out_size, void* d_ws, size_t ws_size,
                              hipStream_t stream)
{
    const int*   A_row     = (const int*)  d_in[0];
    const int*   A_col     = (const int*)  d_in[1];
    const float* A_val     = (const float*)d_in[2];
    const float* user_feat = (const float*)d_in[3];
    const float* item_feat = (const float*)d_in[4];
    const float* W         = (const float*)d_in[5];
    const float* b         = (const float*)d_in[6];
    float*       out       = (float*)d_out;

    const size_t a256 = 255;
    const size_t transh_bytes = (((size_t)N_TOTAL * D * sizeof(__half)) + a256) & ~a256; // 38.4 MB
    const size_t rowoff_bytes = (((size_t)N_TOTAL * sizeof(int)) + a256) & ~a256;        // 1.2 MB
    const size_t gbcnt_bytes  = (((size_t)NBUCK * sizeof(int)) + a256) & ~a256;
    const size_t boff_bytes   = (((size_t)(NBUCK + 1) * sizeof(int)) + a256) & ~a256;
    const size_t gcur_bytes   = (((size_t)NBUCK * sizeof(int)) + a256) & ~a256;
    const size_t eids_bytes   = (((size_t)N_EDGES * sizeof(int)) + a256) & ~a256;        // 24 MB
    const size_t epack_bytes  = (size_t)N_EDGES * sizeof(int2);                          // 48 MB
    const size_t main_total   = transh_bytes + rowoff_bytes + gbcnt_bytes + boff_bytes
                              + gcur_bytes + eids_bytes + epack_bytes;                   // ~111.7 MB

    const size_t trans_bytes  = (size_t)N_TOTAL * D * sizeof(float);                     // fallback

    const int row_blocks = (N_TOTAL + 3) / 4;
    const int lin_blocks = (N_TOTAL + 63) / 64;

    if (ws_size >= main_total) {
        char* p = (char*)d_ws;
        __half* transh = (__half*)p;  p += transh_bytes;
        int*    rowoff = (int*)p;     p += rowoff_bytes;
        int*    gbcnt  = (int*)p;     p += gbcnt_bytes;
        int*    boff   = (int*)p;     p += boff_bytes;
        int*    gcur   = (int*)p;     p += gcur_bytes;
        int*    eids   = (int*)p;     p += eids_bytes;
        int2*   epack  = (int2*)p;

        hipMemsetAsync(gbcnt, 0, (size_t)NBUCK * sizeof(int), stream);
        linear_mfma_kernel<<<lin_blocks, 256, 0, stream>>>(
            user_feat, item_feat, W, b, transh);
        bucket_hist_kernel<<<NPB, 256, 0, stream>>>(A_row, gbcnt);
        bucket_scan_kernel<<<1, 512, 0, stream>>>(gbcnt, boff, gcur);
        partition_kernel<<<NPB, 256, 0, stream>>>(A_row, gcur, eids);
        bucket_csr_kernel<<<NBUCK, 256, 0, stream>>>(
            boff, eids, A_row, A_col, A_val, rowoff, epack);
        pull_half_kernel<<<row_blocks, 256, 0, stream>>>(
            rowoff, epack, transh, user_feat, item_feat, out);
    } else if (ws_size >= trans_bytes) {
        float* trans = (float*)d_ws;
        linear_kernel<<<row_blocks, 256, 0, stream>>>(
            user_feat, item_feat, W, b, trans, out);
        edge_scatter_kernel<<<N_EDGES / 4, 256, 0, stream>>>(
            A_row, A_col, A_val, trans, out);
    } else {
        const size_t total = (size_t)N_TOTAL * D;
        init_out_kernel<<<(int)((total + 255) / 256), 256, 0, stream>>>(
            user_feat, item_feat, out);
        fused_edge_kernel<<<N_EDGES / 4, 256, 0, stream>>>(
            A_row, A_col, A_val, user_feat, item_feat, W, b, out);
    }
}

// Round 8
// 513.333 us; speedup vs baseline: 5.8611x; 1.4251x over previous
//
#include <hip/hip_runtime.h>
#include <hip/hip_fp16.h>

#define N_USERS 100000
#define N_ITEMS 200000
#define N_TOTAL 300000
#define N_EDGES 6000000
#define D 64

#define BSHIFT 10
#define BROWS 1024                                // rows per bucket
#define NBUCK ((N_TOTAL + BROWS - 1) / BROWS)     // 293
#define EPB 4096                                  // edges per partition block
#define NPB ((N_EDGES + EPB - 1) / EPB)           // 1465

typedef float    f32x4 __attribute__((ext_vector_type(4)));
typedef _Float16 f16x8 __attribute__((ext_vector_type(8)));

// ---------------------------------------------------------------------------
// Linear via MFMA: trans(fp16) = all_feat @ W^T + b.  (R7-verified)
// ---------------------------------------------------------------------------
__global__ __launch_bounds__(256) void linear_mfma_kernel(
    const float* __restrict__ user_feat,
    const float* __restrict__ item_feat,
    const float* __restrict__ W,
    const float* __restrict__ bias,
    __half* __restrict__ trans)
{
    const int lane = threadIdx.x & 63;
    const int wv   = threadIdx.x >> 6;
    const int r0   = blockIdx.x * 64 + wv * 16;
    const int arow = lane & 15;
    const int kg   = lane >> 4;

    f16x8 wf[4][2];
    #pragma unroll
    for (int ct = 0; ct < 4; ++ct) {
        const float* wp = W + (size_t)(ct * 16 + arow) * D;
        #pragma unroll
        for (int kf = 0; kf < 2; ++kf) {
            const int k0 = kf * 32 + kg * 8;
            const float4 w0 = *reinterpret_cast<const float4*>(wp + k0);
            const float4 w1 = *reinterpret_cast<const float4*>(wp + k0 + 4);
            f16x8 h;
            h[0] = (_Float16)w0.x; h[1] = (_Float16)w0.y;
            h[2] = (_Float16)w0.z; h[3] = (_Float16)w0.w;
            h[4] = (_Float16)w1.x; h[5] = (_Float16)w1.y;
            h[6] = (_Float16)w1.z; h[7] = (_Float16)w1.w;
            wf[ct][kf] = h;
        }
    }

    int rr = r0 + arow;
    if (rr >= N_TOTAL) rr = N_TOTAL - 1;
    const float* fp = (rr < N_USERS) ? user_feat + (size_t)rr * D
                                     : item_feat + (size_t)(rr - N_USERS) * D;
    f16x8 af[2];
    #pragma unroll
    for (int kf = 0; kf < 2; ++kf) {
        const int k0 = kf * 32 + kg * 8;
        const float4 a0 = *reinterpret_cast<const float4*>(fp + k0);
        const float4 a1 = *reinterpret_cast<const float4*>(fp + k0 + 4);
        f16x8 h;
        h[0] = (_Float16)a0.x; h[1] = (_Float16)a0.y;
        h[2] = (_Float16)a0.z; h[3] = (_Float16)a0.w;
        h[4] = (_Float16)a1.x; h[5] = (_Float16)a1.y;
        h[6] = (_Float16)a1.z; h[7] = (_Float16)a1.w;
        af[kf] = h;
    }

    #pragma unroll
    for (int ct = 0; ct < 4; ++ct) {
        const float bc = bias[ct * 16 + arow];
        f32x4 acc = {bc, bc, bc, bc};
        acc = __builtin_amdgcn_mfma_f32_16x16x32_f16(af[0], wf[ct][0], acc, 0, 0, 0);
        acc = __builtin_amdgcn_mfma_f32_16x16x32_f16(af[1], wf[ct][1], acc, 0, 0, 0);
        #pragma unroll
        for (int reg = 0; reg < 4; ++reg) {
            const int ro = r0 + kg * 4 + reg;
            if (ro < N_TOTAL)
                trans[(size_t)ro * D + ct * 16 + arow] = __float2half(acc[reg]);
        }
    }
}

// ---------------------------------------------------------------------------
// Bucket histogram: per-block LDS counts, one global atomic per bucket.
// ---------------------------------------------------------------------------
__global__ __launch_bounds__(256) void bucket_hist_kernel(
    const int* __restrict__ A_row, int* __restrict__ gbcnt)
{
    __shared__ int lcnt[NBUCK];
    for (int i = threadIdx.x; i < NBUCK; i += 256) lcnt[i] = 0;
    __syncthreads();
    const int base = blockIdx.x * EPB;
    #pragma unroll
    for (int j = 0; j < 4; ++j) {
        const int e0 = base + j * 1024 + threadIdx.x * 4;
        if (e0 < N_EDGES) {
            const int4 r = *reinterpret_cast<const int4*>(A_row + e0);
            atomicAdd(&lcnt[r.x >> BSHIFT], 1);
            atomicAdd(&lcnt[r.y >> BSHIFT], 1);
            atomicAdd(&lcnt[r.z >> BSHIFT], 1);
            atomicAdd(&lcnt[r.w >> BSHIFT], 1);
        }
    }
    __syncthreads();
    for (int i = threadIdx.x; i < NBUCK; i += 256)
        if (lcnt[i]) atomicAdd(&gbcnt[i], lcnt[i]);
}

// ---------------------------------------------------------------------------
// Exclusive scan over NBUCK bucket counts -> boff (starts) and gcur (cursors).
// ---------------------------------------------------------------------------
__global__ __launch_bounds__(512) void bucket_scan_kernel(
    const int* __restrict__ gbcnt, int* __restrict__ boff, int* __restrict__ gcur)
{
    __shared__ int s[512];
    const int t = threadIdx.x;
    s[t] = (t < NBUCK) ? gbcnt[t] : 0;
    __syncthreads();
    for (int d2 = 1; d2 < 512; d2 <<= 1) {
        const int x = (t >= d2) ? s[t - d2] : 0;
        __syncthreads();
        s[t] += x;
        __syncthreads();
    }
    if (t < NBUCK) {
        const int excl = (t == 0) ? 0 : s[t - 1];
        boff[t] = excl;
        gcur[t] = excl;
    }
    if (t == 0) boff[NBUCK] = N_EDGES;
}

// ---------------------------------------------------------------------------
// Pass 1: 293-way partition. Payload moves WITH the partition:
// k1[pos] = (local_row<<19)|col (4B), v1h[pos] = fp16(val) (2B), written in
// block-contiguous runs. Removes all random gathers from pass 2.
// ---------------------------------------------------------------------------
__global__ __launch_bounds__(256) void partition_kernel(
    const int*   __restrict__ A_row,
    const int*   __restrict__ A_col,
    const float* __restrict__ A_val,
    int*    __restrict__ gcur,
    int*    __restrict__ k1,
    __half* __restrict__ v1h)
{
    __shared__ int lcnt[NBUCK];
    __shared__ int gb[NBUCK];
    for (int i = threadIdx.x; i < NBUCK; i += 256) lcnt[i] = 0;
    __syncthreads();

    const int base = blockIdx.x * EPB;
    int pk[16];
    #pragma unroll
    for (int j = 0; j < 4; ++j) {
        const int e0 = base + j * 1024 + threadIdx.x * 4;
        if (e0 < N_EDGES) {
            const int4 r = *reinterpret_cast<const int4*>(A_row + e0);
            pk[4*j+0] = ((r.x >> BSHIFT) << 13) | atomicAdd(&lcnt[r.x >> BSHIFT], 1);
            pk[4*j+1] = ((r.y >> BSHIFT) << 13) | atomicAdd(&lcnt[r.y >> BSHIFT], 1);
            pk[4*j+2] = ((r.z >> BSHIFT) << 13) | atomicAdd(&lcnt[r.z >> BSHIFT], 1);
            pk[4*j+3] = ((r.w >> BSHIFT) << 13) | atomicAdd(&lcnt[r.w >> BSHIFT], 1);
        }
    }
    __syncthreads();
    for (int i = threadIdx.x; i < NBUCK; i += 256)
        gb[i] = lcnt[i] ? atomicAdd(&gcur[i], lcnt[i]) : 0;
    __syncthreads();

    #pragma unroll
    for (int j = 0; j < 4; ++j) {
        const int e0 = base + j * 1024 + threadIdx.x * 4;
        if (e0 < N_EDGES) {
            const int4   r = *reinterpret_cast<const int4*>(A_row + e0);
            const int4   c = *reinterpret_cast<const int4*>(A_col + e0);
            const float4 v = *reinterpret_cast<const float4*>(A_val + e0);
            const int rr[4] = {r.x, r.y, r.z, r.w};
            const int cc[4] = {c.x, c.y, c.z, c.w};
            const float vv[4] = {v.x, v.y, v.z, v.w};
            #pragma unroll
            for (int q = 0; q < 4; ++q) {
                const int p   = pk[4*j+q];
                const int pos = gb[p >> 13] + (p & 0x1FFF);
                k1[pos]  = ((rr[q] & (BROWS - 1)) << 19) | cc[q];
                v1h[pos] = __float2half(vv[q]);
            }
        }
    }
}

// ---------------------------------------------------------------------------
// Pass 2: one block (512 thr) per bucket. STREAMING reads of k1/v1h, row-CSR
// in LDS (native int ds_add), ordered (col, f32 val) written to the bucket's
// private region. Emits rowoff[row] = end-of-row.
// ---------------------------------------------------------------------------
__global__ __launch_bounds__(512) void bucket_csr_kernel(
    const int*    __restrict__ boff,
    const int*    __restrict__ k1,
    const __half* __restrict__ v1h,
    int*  __restrict__ rowoff,
    int2* __restrict__ epack)
{
    __shared__ int rcnt[BROWS];
    __shared__ int rcur[BROWS];
    __shared__ int s[512];
    const int b  = blockIdx.x;
    const int t  = threadIdx.x;
    const int s0 = boff[b], s1 = boff[b + 1];

    for (int i = t; i < BROWS; i += 512) rcnt[i] = 0;
    __syncthreads();

    for (int i = s0 + t; i < s1; i += 512)
        atomicAdd(&rcnt[k1[i] >> 19], 1);
    __syncthreads();

    // exclusive scan rcnt -> rcur (512 threads x 2 items)
    const int v0 = rcnt[t * 2], v1 = rcnt[t * 2 + 1];
    s[t] = v0 + v1;
    __syncthreads();
    for (int d2 = 1; d2 < 512; d2 <<= 1) {
        const int x = (t >= d2) ? s[t - d2] : 0;
        __syncthreads();
        s[t] += x;
        __syncthreads();
    }
    const int run = (t == 0) ? 0 : s[t - 1];
    rcur[t * 2]     = run;
    rcur[t * 2 + 1] = run + v0;
    __syncthreads();

    for (int i = s0 + t; i < s1; i += 512) {
        const int k  = k1[i];
        const int lr = k >> 19;
        const int p  = s0 + atomicAdd(&rcur[lr], 1);
        epack[p] = make_int2(k & 0x7FFFF, __float_as_int(__half2float(v1h[i])));
    }
    __syncthreads();

    const int rbase = b << BSHIFT;
    for (int i = t; i < BROWS; i += 512) {
        const int row = rbase + i;
        if (row < N_TOTAL) rowoff[row] = s0 + rcur[i];   // = end of row
    }
}

// ---------------------------------------------------------------------------
// Pull: one wave per row, lane = column. 8-wide unroll; fp16 trans gathers.
// ---------------------------------------------------------------------------
__global__ __launch_bounds__(256) void pull_half_kernel(
    const int*    __restrict__ rowoff,
    const int2*   __restrict__ epack,
    const __half* __restrict__ trans,
    const float*  __restrict__ user_feat,
    const float*  __restrict__ item_feat,
    float* __restrict__ out)
{
    const int lane = threadIdx.x & 63;
    const int row  = blockIdx.x * 4 + (threadIdx.x >> 6);
    if (row >= N_TOTAL) return;

    const float* feat = (row < N_USERS)
        ? user_feat + (size_t)row * D
        : item_feat + (size_t)(row - N_USERS) * D;

    float a0 = feat[lane];            // identity residual
    float a1 = 0.f, a2 = 0.f, a3 = 0.f, a4 = 0.f, a5 = 0.f, a6 = 0.f, a7 = 0.f;

    const int s   = (row == 0) ? 0 : rowoff[row - 1];
    const int end = rowoff[row];

    int i = s;
    for (; i + 7 < end; i += 8) {
        const int2 p0 = epack[i    ], p1 = epack[i + 1];
        const int2 p2 = epack[i + 2], p3 = epack[i + 3];
        const int2 p4 = epack[i + 4], p5 = epack[i + 5];
        const int2 p6 = epack[i + 6], p7 = epack[i + 7];
        const float t0 = __half2float(trans[((size_t)p0.x << 6) | lane]);
        const float t1 = __half2float(trans[((size_t)p1.x << 6) | lane]);
        const float t2 = __half2float(trans[((size_t)p2.x << 6) | lane]);
        const float t3 = __half2float(trans[((size_t)p3.x << 6) | lane]);
        const float t4 = __half2float(trans[((size_t)p4.x << 6) | lane]);
        const float t5 = __half2float(trans[((size_t)p5.x << 6) | lane]);
        const float t6 = __half2float(trans[((size_t)p6.x << 6) | lane]);
        const float t7 = __half2float(trans[((size_t)p7.x << 6) | lane]);
        a0 = fmaf(__int_as_float(p0.y), t0, a0);
        a1 = fmaf(__int_as_float(p1.y), t1, a1);
        a2 = fmaf(__int_as_float(p2.y), t2, a2);
        a3 = fmaf(__int_as_float(p3.y), t3, a3);
        a4 = fmaf(__int_as_float(p4.y), t4, a4);
        a5 = fmaf(__int_as_float(p5.y), t5, a5);
        a6 = fmaf(__int_as_float(p6.y), t6, a6);
        a7 = fmaf(__int_as_float(p7.y), t7, a7);
    }
    for (; i < end; ++i) {
        const int2 p = epack[i];
        a0 = fmaf(__int_as_float(p.y),
                  __half2float(trans[((size_t)p.x << 6) | lane]), a0);
    }
    out[(size_t)row * D + lane] = ((a0 + a1) + (a2 + a3)) + ((a4 + a5) + (a6 + a7));
}

// ---------------------------------------------------------------------------
// Fallback kernels (small workspace): atomic push path (passed in R1).
// ---------------------------------------------------------------------------
__global__ __launch_bounds__(256) void linear_kernel(
    const float* __restrict__ user_feat,
    const float* __restrict__ item_feat,
    const float* __restrict__ W,
    const float* __restrict__ b,
    float* __restrict__ trans,
    float* __restrict__ out)
{
    __shared__ float Ws[D][D + 1];
    __shared__ float bs[D];
    const int t = threadIdx.x;
    for (int i = t; i < D * D; i += 256) Ws[i >> 6][i & 63] = W[i];
    if (t < D) bs[t] = b[t];
    __syncthreads();

    const int lane = t & 63;
    const int row  = blockIdx.x * 4 + (t >> 6);
    if (row >= N_TOTAL) return;

    const float* feat = (row < N_USERS)
        ? user_feat + (size_t)row * D
        : item_feat + (size_t)(row - N_USERS) * D;

    const float fv = feat[lane];
    float acc = bs[lane];
    #pragma unroll
    for (int k = 0; k < D; ++k)
        acc = fmaf(__shfl(fv, k, 64), Ws[lane][k], acc);

    const size_t off = (size_t)row * D + lane;
    trans[off] = acc;
    if (out) out[off] = fv;
}

__global__ __launch_bounds__(256) void edge_scatter_kernel(
    const int*   __restrict__ A_row,
    const int*   __restrict__ A_col,
    const float* __restrict__ A_val,
    const float* __restrict__ trans,
    float*       __restrict__ out)
{
    const int lane = threadIdx.x & 63;
    const long long e = ((long long)blockIdx.x * 256 + threadIdx.x) >> 6;
    if (e >= N_EDGES) return;
    atomicAdd(out + (size_t)A_row[e] * D + lane,
              A_val[e] * trans[(size_t)A_col[e] * D + lane]);
}

__global__ __launch_bounds__(256) void init_out_kernel(
    const float* __restrict__ user_feat,
    const float* __restrict__ item_feat,
    float* __restrict__ out)
{
    const size_t i = (size_t)blockIdx.x * 256 + threadIdx.x;
    if (i >= (size_t)N_TOTAL * D) return;
    const size_t urows = (size_t)N_USERS * D;
    out[i] = (i < urows) ? user_feat[i] : item_feat[i - urows];
}

__global__ __launch_bounds__(256) void fused_edge_kernel(
    const int*   __restrict__ A_row,
    const int*   __restrict__ A_col,
    const float* __restrict__ A_val,
    const float* __restrict__ user_feat,
    const float* __restrict__ item_feat,
    const float* __restrict__ W,
    const float* __restrict__ b,
    float*       __restrict__ out)
{
    __shared__ float Ws[D][D + 1];
    __shared__ float bs[D];
    const int t = threadIdx.x;
    for (int i = t; i < D * D; i += 256) Ws[i >> 6][i & 63] = W[i];
    if (t < D) bs[t] = b[t];
    __syncthreads();

    const int lane = t & 63;
    const long long e = ((long long)blockIdx.x * 256 + t) >> 6;
    if (e >= N_EDGES) return;

    const int   r = A_row[e];
    const int   c = A_col[e];
    const float v = A_val[e];

    const float* feat = (c < N_USERS)
        ? user_feat + (size_t)c * D
        : item_feat + (size_t)(c - N_USERS) * D;

    const float fv = feat[lane];
    float acc = bs[lane];
    #pragma unroll
    for (int k = 0; k < D; ++k)
        acc = fmaf(__shfl(fv, k, 64), Ws[lane][k], acc);

    atomicAdd(out + (size_t)r * D + lane, v * acc);
}

// ---------------------------------------------------------------------------
extern "C" void kernel_launch(void* const* d_in, const int* in_sizes, int n_in,
                              void* d_out, int out_size, void* d_ws, size_t ws_size,
                              hipStream_t stream)
{
    const int*   A_row     = (const int*)  d_in[0];
    const int*   A_col     = (const int*)  d_in[1];
    const float* A_val     = (const float*)d_in[2];
    const float* user_feat = (const float*)d_in[3];
    const float* item_feat = (const float*)d_in[4];
    const float* W         = (const float*)d_in[5];
    const float* b         = (const float*)d_in[6];
    float*       out       = (float*)d_out;

    const size_t a256 = 255;
    const size_t transh_bytes = (((size_t)N_TOTAL * D * sizeof(__half)) + a256) & ~a256; // 38.4 MB
    const size_t rowoff_bytes = (((size_t)N_TOTAL * sizeof(int)) + a256) & ~a256;        // 1.2 MB
    const size_t gbcnt_bytes  = (((size_t)NBUCK * sizeof(int)) + a256) & ~a256;
    const size_t boff_bytes   = (((size_t)(NBUCK + 1) * sizeof(int)) + a256) & ~a256;
    const size_t gcur_bytes   = (((size_t)NBUCK * sizeof(int)) + a256) & ~a256;
    const size_t k1_bytes     = (((size_t)N_EDGES * sizeof(int)) + a256) & ~a256;        // 24 MB
    const size_t v1h_bytes    = (((size_t)N_EDGES * sizeof(__half)) + a256) & ~a256;     // 12 MB
    const size_t epack_bytes  = (size_t)N_EDGES * sizeof(int2);                          // 48 MB
    const size_t main_total   = transh_bytes + rowoff_bytes + gbcnt_bytes + boff_bytes
                              + gcur_bytes + k1_bytes + v1h_bytes + epack_bytes;         // ~123.7 MB

    const size_t trans_bytes  = (size_t)N_TOTAL * D * sizeof(float);                     // fallback

    const int row_blocks = (N_TOTAL + 3) / 4;
    const int lin_blocks = (N_TOTAL + 63) / 64;

    if (ws_size >= main_total) {
        char* p = (char*)d_ws;
        __half* transh = (__half*)p;  p += transh_bytes;
        int*    rowoff = (int*)p;     p += rowoff_bytes;
        int*    gbcnt  = (int*)p;     p += gbcnt_bytes;
        int*    boff   = (int*)p;     p += boff_bytes;
        int*    gcur   = (int*)p;     p += gcur_bytes;
        int*    k1     = (int*)p;     p += k1_bytes;
        __half* v1h    = (__half*)p;  p += v1h_bytes;
        int2*   epack  = (int2*)p;

        hipMemsetAsync(gbcnt, 0, (size_t)NBUCK * sizeof(int), stream);
        linear_mfma_kernel<<<lin_blocks, 256, 0, stream>>>(
            user_feat, item_feat, W, b, transh);
        bucket_hist_kernel<<<NPB, 256, 0, stream>>>(A_row, gbcnt);
        bucket_scan_kernel<<<1, 512, 0, stream>>>(gbcnt, boff, gcur);
        partition_kernel<<<NPB, 256, 0, stream>>>(
            A_row, A_col, A_val, gcur, k1, v1h);
        bucket_csr_kernel<<<NBUCK, 512, 0, stream>>>(
            boff, k1, v1h, rowoff, epack);
        pull_half_kernel<<<row_blocks, 256, 0, stream>>>(
            rowoff, epack, transh, user_feat, item_feat, out);
    } else if (ws_size >= trans_bytes) {
        float* trans = (float*)d_ws;
        linear_kernel<<<row_blocks, 256, 0, stream>>>(
            user_feat, item_feat, W, b, trans, out);
        edge_scatter_kernel<<<N_EDGES / 4, 256, 0, stream>>>(
            A_row, A_col, A_val, trans, out);
    } else {
        const size_t total = (size_t)N_TOTAL * D;
        init_out_kernel<<<(int)((total + 255) / 256), 256, 0, stream>>>(
            user_feat, item_feat, out);
        fused_edge_kernel<<<N_EDGES / 4, 256, 0, stream>>>(
            A_row, A_col, A_val, user_feat, item_feat, W, b, out);
    }
}